// Round 9
// baseline (69.599 us; speedup 1.0000x reference)
//
#include <hip/hip_runtime.h>

// out = x @ ((B@A - B0@A0) * s)  ==  ((x@[B|-B0]) @ [A;A0]) * s,  s = 1.
// x[8192][4096] fp32, A/A0[16][4096], B/B0[4096][16].
// Fused row-local kernel: per 16-row tile, GEMM1 (K=4096 via MFMA, split
// across 4 waves, LDS-reduced) then GEMM2 (K=32, one MFMA depth).
// R8: 4 waves + 128-VGPR budget + explicit depth-4 register prefetch in
// Phase A (R7's 8-wave/32-VGPR config collapsed per-wave load ILP).
#define N_TOK 8192
#define D     4096
#define RLO   16
#define R2    32

typedef __bf16  bf16x8  __attribute__((ext_vector_type(8)));
typedef short   short8v __attribute__((ext_vector_type(8)));
typedef float   f32x4   __attribute__((ext_vector_type(4)));

__device__ __forceinline__ short bf1(float f) {
  __bf16 b = (__bf16)f;
  return __builtin_bit_cast(short, b);
}

__device__ __forceinline__ short8v cvt8(float4 lo, float4 hi) {
  bf16x8 b;
  b[0] = (__bf16)lo.x; b[1] = (__bf16)lo.y; b[2] = (__bf16)lo.z; b[3] = (__bf16)lo.w;
  b[4] = (__bf16)hi.x; b[5] = (__bf16)hi.y; b[6] = (__bf16)hi.z; b[7] = (__bf16)hi.w;
  return __builtin_bit_cast(short8v, b);
}

// d_ws layout: PTb [32][4096] bf16 (256 KB) | Qpk [4096][32] bf16 (256 KB)

__global__ __launch_bounds__(256) void prep_kernel(
    const float* __restrict__ A, const float* __restrict__ B,
    const float* __restrict__ A0, const float* __restrict__ B0,
    ushort* __restrict__ PTb, ushort* __restrict__ Qpk) {
  int idx = blockIdx.x * 256 + threadIdx.x;   // 0 .. 32*4096-1
  int r = idx >> 12;
  int k = idx & (D - 1);
  float pt, q;
  if (r < RLO) {
    pt = B[k * RLO + r];
    q  = A[r * D + k];
  } else {
    pt = -B0[k * RLO + (r - RLO)];
    q  = A0[(r - RLO) * D + k];
  }
  PTb[idx] = (ushort)bf1(pt);                 // [r][k], k contiguous
  Qpk[(size_t)k * R2 + r] = (ushort)bf1(q);   // [j][r], r contiguous
}

// Fused: per 16-row tile, 4 waves.
// Phase A: wave w accumulates k in [w*1024, w*1024+1024) via 32 MFMA k-steps
//   with a depth-4 register prefetch pipeline (16 KB/wave in flight);
//   4 wave-partials LDS-reduced; u tile -> bf16 in LDS.
// Phase B: wave w covers j in [w*1024, w*1024+1024): 64 MFMA tiles, nt stores.
__global__ __launch_bounds__(256, 4) void fused_kernel(
    const float* __restrict__ x, const ushort* __restrict__ PTb,
    const ushort* __restrict__ Qpk, float* __restrict__ out) {
  __shared__ float red[4][16][R2 + 2];           // padded: conflict-free reduce
  __shared__ __align__(16) ushort usb[16][R2];   // u tile in bf16, 1 KB
  const int tid  = threadIdx.x;
  const int w    = tid >> 6;
  const int lane = tid & 63;
  const int l16  = lane & 15;
  const int kg   = lane >> 4;
  const int row0 = blockIdx.x * 16;
  const int kb   = w * 1024 + kg * 8;

  // ---- Phase A: u[row0..row0+15][0..31] ----
  const float*  xp  = x   + (size_t)(row0 + l16) * D + kb;
  const ushort* pb0 = PTb + (size_t)l16 * D + kb;
  const ushort* pb1 = pb0 + (size_t)16 * D;

  // depth-4 register prefetch pipeline
  float4  pxa[4], pxb[4];
  short8v pr0[4], pr1[4];
#pragma unroll
  for (int d = 0; d < 4; ++d) {
    const int ko = d * 32;
    pxa[d] = *(const float4*)(xp + ko);
    pxb[d] = *(const float4*)(xp + ko + 4);
    pr0[d] = *(const short8v*)(pb0 + ko);
    pr1[d] = *(const short8v*)(pb1 + ko);
  }

  f32x4 acc0 = {0.f, 0.f, 0.f, 0.f};
  f32x4 acc1 = {0.f, 0.f, 0.f, 0.f};

#pragma unroll
  for (int s = 0; s < 32; ++s) {
    const int d = s & 3;
    const short8v a  = cvt8(pxa[d], pxb[d]);
    const short8v b0 = pr0[d];
    const short8v b1 = pr1[d];
    if (s + 4 < 32) {                 // refill slot d for iteration s+4
      const int ko = (s + 4) * 32;
      pxa[d] = *(const float4*)(xp + ko);
      pxb[d] = *(const float4*)(xp + ko + 4);
      pr0[d] = *(const short8v*)(pb0 + ko);
      pr1[d] = *(const short8v*)(pb1 + ko);
    }
    acc0 = __builtin_amdgcn_mfma_f32_16x16x32_bf16(a, b0, acc0, 0, 0, 0);
    acc1 = __builtin_amdgcn_mfma_f32_16x16x32_bf16(a, b1, acc1, 0, 0, 0);
  }

  // D-frag: col = lane&15 (= r), row = (lane>>4)*4 + j (= local x-row)
#pragma unroll
  for (int j = 0; j < 4; ++j) {
    red[w][kg * 4 + j][l16]      = acc0[j];
    red[w][kg * 4 + j][16 + l16] = acc1[j];
  }
  __syncthreads();

  // 512 cells (16 rows x 32 r); 256 threads handle 2 each; sum 4 waves -> bf16
#pragma unroll
  for (int half = 0; half < 2; ++half) {
    const int idx = half * 256 + tid;
    const int row = idx >> 5;
    const int r   = idx & 31;
    const float s = red[0][row][r] + red[1][row][r] +
                    red[2][row][r] + red[3][row][r];
    usb[row][r] = (ushort)bf1(s);
  }
  __syncthreads();

  // ---- Phase B: out[row0..row0+15][:] = u_tile @ Q ----
  const short8v ua = *(const short8v*)&usb[l16][kg * 8];
  const f32x4 z = {0.f, 0.f, 0.f, 0.f};
  const int jbase = w * 1024;

#pragma unroll 8
  for (int jt = 0; jt < 64; ++jt) {
    const int j = jbase + jt * 16 + l16;
    const short8v qb = *(const short8v*)(Qpk + (size_t)j * R2 + kg * 8);
    const f32x4 d = __builtin_amdgcn_mfma_f32_16x16x32_bf16(ua, qb, z, 0, 0, 0);
    float* o = out + (size_t)(row0 + kg * 4) * D + j;
#pragma unroll
    for (int jr = 0; jr < 4; ++jr)
      __builtin_nontemporal_store(d[jr], o + (size_t)jr * D);
  }
}

extern "C" void kernel_launch(void* const* d_in, const int* in_sizes, int n_in,
                              void* d_out, int out_size, void* d_ws, size_t ws_size,
                              hipStream_t stream) {
  const float* x  = (const float*)d_in[0];
  const float* A  = (const float*)d_in[1];
  const float* B  = (const float*)d_in[2];
  const float* A0 = (const float*)d_in[3];
  const float* B0 = (const float*)d_in[4];
  float* out = (float*)d_out;

  ushort* PTb = (ushort*)d_ws;               // 32*4096 bf16
  ushort* Qpk = PTb + (size_t)R2 * D;        // 4096*32 bf16

  hipLaunchKernelGGL(prep_kernel, dim3((R2 * D) / 256), dim3(256), 0, stream,
                     A, B, A0, B0, PTb, Qpk);
  hipLaunchKernelGGL(fused_kernel, dim3(N_TOK / 16), dim3(256), 0, stream,
                     x, PTb, Qpk, out);
}

// Round 11
// 65.263 us; speedup vs baseline: 1.0664x; 1.0664x over previous
//
#include <hip/hip_runtime.h>

// out = x @ ((B@A - B0@A0) * s)  ==  ((x@[B|-B0]) @ [A;A0]) * s,  s = 1.
// x[8192][4096] fp32, A/A0[16][4096], B/B0[4096][16].
// Fused row-local kernel (R6 structure). Phase A load pipeline forced with
// asm-volatile global_load_dwordx4 + counted s_waitcnt vmcnt + sched_barrier
// fences (compiler refuses source-level prefetch: R7/R8 VGPR=32).
// R10 fix vs R9: xb offset is 128*S+16 (was +64: wrong data + OOB crash);
// trailing sched_barrier(0) pins each step's compute before the next loads
// (register slot reuse hazard, no HW scoreboard).
#define N_TOK 8192
#define D     4096
#define RLO   16
#define R2    32

typedef __bf16  bf16x8  __attribute__((ext_vector_type(8)));
typedef short   short8v __attribute__((ext_vector_type(8)));
typedef float   f32x4   __attribute__((ext_vector_type(4)));

__device__ __forceinline__ short bf1(float f) {
  __bf16 b = (__bf16)f;
  return __builtin_bit_cast(short, b);
}

__device__ __forceinline__ short8v cvt8(float4 lo, float4 hi) {
  bf16x8 b;
  b[0] = (__bf16)lo.x; b[1] = (__bf16)lo.y; b[2] = (__bf16)lo.z; b[3] = (__bf16)lo.w;
  b[4] = (__bf16)hi.x; b[5] = (__bf16)hi.y; b[6] = (__bf16)hi.z; b[7] = (__bf16)hi.w;
  return __builtin_bit_cast(short8v, b);
}

// d_ws layout: PTb [32][4096] bf16 (256 KB) | Qpk [4096][32] bf16 (256 KB)

__global__ __launch_bounds__(256) void prep_kernel(
    const float* __restrict__ A, const float* __restrict__ B,
    const float* __restrict__ A0, const float* __restrict__ B0,
    ushort* __restrict__ PTb, ushort* __restrict__ Qpk) {
  int idx = blockIdx.x * 256 + threadIdx.x;   // 0 .. 32*4096-1
  int r = idx >> 12;
  int k = idx & (D - 1);
  float pt, q;
  if (r < RLO) {
    pt = B[k * RLO + r];
    q  = A[r * D + k];
  } else {
    pt = -B0[k * RLO + (r - RLO)];
    q  = A0[(r - RLO) * D + k];
  }
  PTb[idx] = (ushort)bf1(pt);                 // [r][k], k contiguous
  Qpk[(size_t)k * R2 + r] = (ushort)bf1(q);   // [j][r], r contiguous
}

// Issue the 4 loads of k-step S. Lane's 8-float x fragment is CONSECUTIVE:
// xa = floats 32S..32S+3 (byte 128S), xb = floats 32S+4..7 (byte 128S+16).
// PT rows 0-15 / 16-31: 8 bf16 at byte 64S. All offsets <= 3984 (13-bit ok).
#define LOAD_STEP(S)                                                        \
  asm volatile("global_load_dwordx4 %0, %1, off offset:%c2"                 \
               : "=v"(xa[(S) & 3]) : "v"(xp),  "i"(128 * (S)));             \
  asm volatile("global_load_dwordx4 %0, %1, off offset:%c2"                 \
               : "=v"(xb[(S) & 3]) : "v"(xp),  "i"(128 * (S) + 16));        \
  asm volatile("global_load_dwordx4 %0, %1, off offset:%c2"                 \
               : "=v"(b0r[(S) & 3]) : "v"(pb0), "i"(64 * (S)));             \
  asm volatile("global_load_dwordx4 %0, %1, off offset:%c2"                 \
               : "=v"(b1r[(S) & 3]) : "v"(pb1), "i"(64 * (S)));

// Consume k-step S once at most WN vmem ops are outstanding (at step S,
// issued = 4*(S+4); completed >= 4*(S+1) iff outstanding <= 12).
// Leading sched_barrier: MFMA can't hoist above the wait (rule 18).
// Trailing sched_barrier: compute can't sink below the next LOAD_STEP,
// which re-targets the same register slot.
#define COMP_STEP(S, WN)                                                    \
  asm volatile("s_waitcnt vmcnt(%c0)" :: "i"(WN));                          \
  __builtin_amdgcn_sched_barrier(0);                                        \
  {                                                                         \
    const short8v a_ = cvt8(xa[(S) & 3], xb[(S) & 3]);                      \
    acc0 = __builtin_amdgcn_mfma_f32_16x16x32_bf16(a_, b0r[(S) & 3], acc0,  \
                                                   0, 0, 0);                \
    acc1 = __builtin_amdgcn_mfma_f32_16x16x32_bf16(a_, b1r[(S) & 3], acc1,  \
                                                   0, 0, 0);                \
  }                                                                         \
  __builtin_amdgcn_sched_barrier(0);

// Fused: per 16-row tile, 4 waves.
// Phase A: wave w accumulates k in [w*1024, w*1024+1024): 32 MFMA k-steps,
//   asm-pipelined depth 4 (16 loads in flight per wave); LDS-reduce; bf16 u.
// Phase B: wave w covers j in [w*1024, w*1024+1024): 64 MFMA tiles, nt stores.
__global__ __launch_bounds__(256) void fused_kernel(
    const float* __restrict__ x, const ushort* __restrict__ PTb,
    const ushort* __restrict__ Qpk, float* __restrict__ out) {
  __shared__ float red[4][16][R2 + 2];           // padded: conflict-free reduce
  __shared__ __align__(16) ushort usb[16][R2];   // u tile in bf16, 1 KB
  const int tid  = threadIdx.x;
  const int w    = tid >> 6;
  const int lane = tid & 63;
  const int l16  = lane & 15;
  const int kg   = lane >> 4;
  const int row0 = blockIdx.x * 16;
  const int kb   = w * 1024 + kg * 8;

  // ---- Phase A ----
  const float*  xp  = x   + (size_t)(row0 + l16) * D + kb;
  const ushort* pb0 = PTb + (size_t)l16 * D + kb;
  const ushort* pb1 = pb0 + (size_t)16 * D;

  float4  xa[4], xb[4];
  short8v b0r[4], b1r[4];
  f32x4 acc0 = {0.f, 0.f, 0.f, 0.f};
  f32x4 acc1 = {0.f, 0.f, 0.f, 0.f};

  LOAD_STEP(0) LOAD_STEP(1) LOAD_STEP(2) LOAD_STEP(3)

#pragma unroll
  for (int s = 0; s < 28; ++s) {
    COMP_STEP(s, 12)
    LOAD_STEP(s + 4)
  }
  COMP_STEP(28, 12)
  COMP_STEP(29, 8)
  COMP_STEP(30, 4)
  COMP_STEP(31, 0)

  // D-frag: col = lane&15 (= r), row = (lane>>4)*4 + j (= local x-row)
#pragma unroll
  for (int j = 0; j < 4; ++j) {
    red[w][kg * 4 + j][l16]      = acc0[j];
    red[w][kg * 4 + j][16 + l16] = acc1[j];
  }
  __syncthreads();

  // 512 cells (16 rows x 32 r); 256 threads handle 2 each; sum 4 waves -> bf16
#pragma unroll
  for (int half = 0; half < 2; ++half) {
    const int idx = half * 256 + tid;
    const int row = idx >> 5;
    const int r   = idx & 31;
    const float s = red[0][row][r] + red[1][row][r] +
                    red[2][row][r] + red[3][row][r];
    usb[row][r] = (ushort)bf1(s);
  }
  __syncthreads();

  // ---- Phase B: out[row0..row0+15][:] = u_tile @ Q ----
  const short8v ua = *(const short8v*)&usb[l16][kg * 8];
  const f32x4 z = {0.f, 0.f, 0.f, 0.f};
  const int jbase = w * 1024;

#pragma unroll 8
  for (int jt = 0; jt < 64; ++jt) {
    const int j = jbase + jt * 16 + l16;
    const short8v qb = *(const short8v*)(Qpk + (size_t)j * R2 + kg * 8);
    const f32x4 d = __builtin_amdgcn_mfma_f32_16x16x32_bf16(ua, qb, z, 0, 0, 0);
    float* o = out + (size_t)(row0 + kg * 4) * D + j;
#pragma unroll
    for (int jr = 0; jr < 4; ++jr)
      __builtin_nontemporal_store(d[jr], o + (size_t)jr * D);
  }
}

extern "C" void kernel_launch(void* const* d_in, const int* in_sizes, int n_in,
                              void* d_out, int out_size, void* d_ws, size_t ws_size,
                              hipStream_t stream) {
  const float* x  = (const float*)d_in[0];
  const float* A  = (const float*)d_in[1];
  const float* B  = (const float*)d_in[2];
  const float* A0 = (const float*)d_in[3];
  const float* B0 = (const float*)d_in[4];
  float* out = (float*)d_out;

  ushort* PTb = (ushort*)d_ws;               // 32*4096 bf16
  ushort* Qpk = PTb + (size_t)R2 * D;        // 4096*32 bf16

  hipLaunchKernelGGL(prep_kernel, dim3((R2 * D) / 256), dim3(256), 0, stream,
                     A, B, A0, B0, PTb, Qpk);
  hipLaunchKernelGGL(fused_kernel, dim3(N_TOK / 16), dim3(256), 0, stream,
                     x, PTb, Qpk, out);
}